// Round 1
// baseline (518.008 us; speedup 1.0000x reference)
//
#include <hip/hip_runtime.h>
#include <math.h>

#define T_LEN 32768
#define D_DIM 1024
#define LD 4
#define H_DIM 6
#define CHUNK 16
#define WARM 64
#define NCHUNK (T_LEN / CHUNK)

// log(2*pi)
#define LOG2PI 1.8378770664093453f

__device__ __forceinline__ float frcp(float x) {
    float r = __builtin_amdgcn_rcpf(x);
    return r * (2.0f - x * r);   // one Newton step -> ~0.5 ulp
}

// Cholesky of 4x4 SPD S (row-major). Fills lower cL, invd[j] = 1/cL[j][j].
__device__ __forceinline__ void chol4(const float* S, float* cL, float* invd) {
#pragma unroll
    for (int j = 0; j < 4; ++j) {
        float d = S[j * 4 + j];
#pragma unroll
        for (int k = 0; k < j; ++k) d -= cL[j * 4 + k] * cL[j * 4 + k];
        float c = sqrtf(d);
        cL[j * 4 + j] = c;
        float id = frcp(c);
        invd[j] = id;
#pragma unroll
        for (int i = j + 1; i < 4; ++i) {
            float v = S[i * 4 + j];
#pragma unroll
            for (int k = 0; k < j; ++k) v -= cL[i * 4 + k] * cL[j * 4 + k];
            cL[i * 4 + j] = v * id;
        }
    }
}

// X = S^{-1} B  (4 RHS = columns of B), S = cL cL^T
__device__ __forceinline__ void chosolve4(const float* cL, const float* invd,
                                          const float* B, float* X) {
#pragma unroll
    for (int c = 0; c < 4; ++c) {
        float y0 = B[0 * 4 + c] * invd[0];
        float y1 = (B[1 * 4 + c] - cL[4] * y0) * invd[1];
        float y2 = (B[2 * 4 + c] - cL[8] * y0 - cL[9] * y1) * invd[2];
        float y3 = (B[3 * 4 + c] - cL[12] * y0 - cL[13] * y1 - cL[14] * y2) * invd[3];
        float x3 = y3 * invd[3];
        float x2 = (y2 - cL[14] * x3) * invd[2];
        float x1 = (y1 - cL[9] * x2 - cL[13] * x3) * invd[1];
        float x0 = (y0 - cL[4] * x1 - cL[8] * x2 - cL[12] * x3) * invd[0];
        X[0 * 4 + c] = x0; X[1 * 4 + c] = x1; X[2 * 4 + c] = x2; X[3 * 4 + c] = x3;
    }
}

__device__ __forceinline__ void mm4(const float* A, const float* B, float* C) {
#pragma unroll
    for (int i = 0; i < 4; ++i)
#pragma unroll
        for (int j = 0; j < 4; ++j) {
            float s = 0.f;
#pragma unroll
            for (int k = 0; k < 4; ++k) s += A[i * 4 + k] * B[k * 4 + j];
            C[i * 4 + j] = s;
        }
}

// ---------------- encoder: h = relu(xW1+b1); mu = hWmu+bmu; sigma = exp(0.5(hWlv+blv))
__global__ __launch_bounds__(256) void encoder_kernel(
    const float* __restrict__ x, const float* __restrict__ W1, const float* __restrict__ b1,
    const float* __restrict__ Wmu, const float* __restrict__ bmu,
    const float* __restrict__ Wlv, const float* __restrict__ blv,
    float* __restrict__ mu_o, float* __restrict__ sig_o) {
    int lane = threadIdx.x & 63;
    int row = blockIdx.x * 4 + (threadIdx.x >> 6);
    const float4* x4 = reinterpret_cast<const float4*>(x + (size_t)row * D_DIM);
    const float4* w4 = reinterpret_cast<const float4*>(W1);
    float acc[H_DIM];
#pragma unroll
    for (int j = 0; j < H_DIM; ++j) acc[j] = 0.f;
#pragma unroll
    for (int c = 0; c < 4; ++c) {
        int idx4 = c * 64 + lane;      // float4 index within row
        float4 xv = x4[idx4];
        // W1 rows 4*idx4 .. 4*idx4+3 = 24 consecutive floats = 6 float4
        float w[24];
        int wb = idx4 * 6;             // float4 index into W1
#pragma unroll
        for (int q = 0; q < 6; ++q) {
            float4 wv = w4[wb + q];
            w[q * 4 + 0] = wv.x; w[q * 4 + 1] = wv.y; w[q * 4 + 2] = wv.z; w[q * 4 + 3] = wv.w;
        }
        float xe[4] = {xv.x, xv.y, xv.z, xv.w};
#pragma unroll
        for (int e = 0; e < 4; ++e)
#pragma unroll
            for (int j = 0; j < H_DIM; ++j)
                acc[j] += xe[e] * w[e * 6 + j];
    }
#pragma unroll
    for (int off = 32; off; off >>= 1)
#pragma unroll
        for (int j = 0; j < H_DIM; ++j)
            acc[j] += __shfl_xor(acc[j], off, 64);
    float h[H_DIM];
#pragma unroll
    for (int j = 0; j < H_DIM; ++j) h[j] = fmaxf(acc[j] + b1[j], 0.f);
    if (lane < LD) {
        int i = lane;
        float muv = bmu[i], lvv = blv[i];
#pragma unroll
        for (int j = 0; j < H_DIM; ++j) {
            muv += h[j] * Wmu[j * LD + i];
            lvv += h[j] * Wlv[j * LD + i];
        }
        mu_o[(size_t)row * LD + i] = muv;
        sig_o[(size_t)row * LD + i] = expf(0.5f * lvv);
    }
}

// ---------------- filter: chunked Kalman filter with warm-up
__global__ __launch_bounds__(64, 1) void filter_kernel(
    const float* __restrict__ mu, const float* __restrict__ sigma,
    const float* __restrict__ Ain, const float* __restrict__ b_dyn,
    const float* __restrict__ qp,
    float* __restrict__ fm, float* __restrict__ fP,
    float* __restrict__ pm, float* __restrict__ pP, float* __restrict__ ll_out) {
    int chunk = blockIdx.x * blockDim.x + threadIdx.x;
    if (chunk >= NCHUNK) return;

    float a[16], b[4];
#pragma unroll
    for (int i = 0; i < 16; ++i) a[i] = Ain[i];
#pragma unroll
    for (int i = 0; i < 4; ++i) b[i] = b_dyn[i];

    // Q = L L^T, L lower-tri from qp (row-major tril order), diag = exp(raw)
    float Lm[16];
#pragma unroll
    for (int i = 0; i < 16; ++i) Lm[i] = 0.f;
    Lm[0] = expf(qp[0]);
    Lm[4] = qp[1];  Lm[5] = expf(qp[2]);
    Lm[8] = qp[3];  Lm[9] = qp[4];  Lm[10] = expf(qp[5]);
    Lm[12] = qp[6]; Lm[13] = qp[7]; Lm[14] = qp[8]; Lm[15] = expf(qp[9]);
    float Q[16];
#pragma unroll
    for (int i = 0; i < 4; ++i)
#pragma unroll
        for (int j = 0; j < 4; ++j) {
            float s = 0.f;
#pragma unroll
            for (int k = 0; k < 4; ++k) s += Lm[i * 4 + k] * Lm[j * 4 + k];
            Q[i * 4 + j] = s;
        }

    int own_lo = chunk * CHUNK;
    int start = own_lo - WARM;

    float m[4] = {0.f, 0.f, 0.f, 0.f};
    float P[16];
#pragma unroll
    for (int i = 0; i < 16; ++i) P[i] = 0.f;
    P[0] = P[5] = P[10] = P[15] = 1.f;

    float ll_acc = 0.f;
    const float4* mu4 = reinterpret_cast<const float4*>(mu);
    const float4* sg4 = reinterpret_cast<const float4*>(sigma);

    for (int s = 0; s < WARM + CHUNK; ++s) {
        int t = start + s;
        if (t < 0) continue;
        float4 yv = mu4[t];
        float4 rv = sg4[t];
        float y[4] = {yv.x, yv.y, yv.z, yv.w};
        // m_pred = A m + b
        float mp[4];
#pragma unroll
        for (int i = 0; i < 4; ++i) {
            float s0 = b[i];
#pragma unroll
            for (int k = 0; k < 4; ++k) s0 += a[i * 4 + k] * m[k];
            mp[i] = s0;
        }
        // P_pred = A P A^T + Q
        float AP[16];
        mm4(a, P, AP);
        float Pp[16];
#pragma unroll
        for (int i = 0; i < 4; ++i)
#pragma unroll
            for (int j = 0; j < 4; ++j) {
                float s0 = Q[i * 4 + j];
#pragma unroll
                for (int k = 0; k < 4; ++k) s0 += AP[i * 4 + k] * a[j * 4 + k];
                Pp[i * 4 + j] = s0;
            }
        // S = Pp + diag(r)
        float S[16];
#pragma unroll
        for (int i = 0; i < 16; ++i) S[i] = Pp[i];
        S[0] += rv.x; S[5] += rv.y; S[10] += rv.z; S[15] += rv.w;
        float cL[16], invd[4];
        chol4(S, cL, invd);
        // X = S^{-1} Pp ; K = X^T
        float X[16];
        chosolve4(cL, invd, Pp, X);
        float innov[4];
#pragma unroll
        for (int i = 0; i < 4; ++i) innov[i] = y[i] - mp[i];
        float mf[4];
#pragma unroll
        for (int i = 0; i < 4; ++i) {
            float s0 = mp[i];
#pragma unroll
            for (int k = 0; k < 4; ++k) s0 += X[k * 4 + i] * innov[k];  // K[i][k] = X[k][i]
            mf[i] = s0;
        }
        // Pf = (I - K) Pp, symmetrized
        float M[16];
#pragma unroll
        for (int i = 0; i < 4; ++i)
#pragma unroll
            for (int j = 0; j < 4; ++j) {
                float s0 = Pp[i * 4 + j];
#pragma unroll
                for (int k = 0; k < 4; ++k) s0 -= X[k * 4 + i] * Pp[k * 4 + j];
                M[i * 4 + j] = s0;
            }
        float Pf[16];
#pragma unroll
        for (int i = 0; i < 4; ++i)
#pragma unroll
            for (int j = 0; j < 4; ++j)
                Pf[i * 4 + j] = 0.5f * (M[i * 4 + j] + M[j * 4 + i]);
        if (t >= own_lo) {
            // ll
            float w0 = innov[0] * invd[0];
            float w1 = (innov[1] - cL[4] * w0) * invd[1];
            float w2 = (innov[2] - cL[8] * w0 - cL[9] * w1) * invd[2];
            float w3 = (innov[3] - cL[12] * w0 - cL[13] * w1 - cL[14] * w2) * invd[3];
            float wsq = w0 * w0 + w1 * w1 + w2 * w2 + w3 * w3;
            float proddiag = cL[0] * cL[5] * cL[10] * cL[15];
            ll_acc += -0.5f * (4.f * LOG2PI + wsq) - logf(proddiag);
            // stores
            float4* fm4 = reinterpret_cast<float4*>(fm);
            float4* pm4 = reinterpret_cast<float4*>(pm);
            float4* fP4 = reinterpret_cast<float4*>(fP);
            float4* pP4 = reinterpret_cast<float4*>(pP);
            fm4[t] = make_float4(mf[0], mf[1], mf[2], mf[3]);
            pm4[t] = make_float4(mp[0], mp[1], mp[2], mp[3]);
#pragma unroll
            for (int q = 0; q < 4; ++q) {
                fP4[t * 4 + q] = make_float4(Pf[q * 4 + 0], Pf[q * 4 + 1], Pf[q * 4 + 2], Pf[q * 4 + 3]);
                pP4[t * 4 + q] = make_float4(Pp[q * 4 + 0], Pp[q * 4 + 1], Pp[q * 4 + 2], Pp[q * 4 + 3]);
            }
        }
#pragma unroll
        for (int i = 0; i < 4; ++i) m[i] = mf[i];
#pragma unroll
        for (int i = 0; i < 16; ++i) P[i] = Pf[i];
    }
    atomicAdd(ll_out, ll_acc);
}

// ---------------- smoother (+ sampling z)
__global__ __launch_bounds__(64, 1) void smoother_kernel(
    const float* __restrict__ fm, const float* __restrict__ fP,
    const float* __restrict__ pm, const float* __restrict__ pP,
    const float* __restrict__ Ain, const float* __restrict__ eps,
    float* __restrict__ sm, float* __restrict__ sP, float* __restrict__ z) {
    int chunk = blockIdx.x * blockDim.x + threadIdx.x;
    if (chunk >= NCHUNK) return;

    float a[16];
#pragma unroll
    for (int i = 0; i < 16; ++i) a[i] = Ain[i];

    int own_lo = chunk * CHUNK;
    int own_hi = own_lo + CHUNK;

    const float4* fm4 = reinterpret_cast<const float4*>(fm);
    const float4* fP4 = reinterpret_cast<const float4*>(fP);
    const float4* pm4 = reinterpret_cast<const float4*>(pm);
    const float4* pP4 = reinterpret_cast<const float4*>(pP);
    const float4* ep4 = reinterpret_cast<const float4*>(eps);
    float4* sm4 = reinterpret_cast<float4*>(sm);
    float4* sP4 = reinterpret_cast<float4*>(sP);
    float4* z4 = reinterpret_cast<float4*>(z);

    // last chunk writes terminal t = T-1
    if (chunk == NCHUNK - 1) {
        int t = T_LEN - 1;
        float4 mt = fm4[t];
        float Pt[16];
#pragma unroll
        for (int q = 0; q < 4; ++q) {
            float4 v = fP4[t * 4 + q];
            Pt[q * 4 + 0] = v.x; Pt[q * 4 + 1] = v.y; Pt[q * 4 + 2] = v.z; Pt[q * 4 + 3] = v.w;
        }
        sm4[t] = mt;
#pragma unroll
        for (int q = 0; q < 4; ++q)
            sP4[t * 4 + q] = make_float4(Pt[q * 4 + 0], Pt[q * 4 + 1], Pt[q * 4 + 2], Pt[q * 4 + 3]);
        float Sz[16];
#pragma unroll
        for (int i = 0; i < 16; ++i) Sz[i] = Pt[i];
        Sz[0] += 1e-6f; Sz[5] += 1e-6f; Sz[10] += 1e-6f; Sz[15] += 1e-6f;
        float cL[16], invd[4];
        chol4(Sz, cL, invd);
        float4 ev = ep4[t];
        float e[4] = {ev.x, ev.y, ev.z, ev.w};
        float zz[4];
        zz[0] = mt.x + cL[0] * e[0];
        zz[1] = mt.y + cL[4] * e[0] + cL[5] * e[1];
        zz[2] = mt.z + cL[8] * e[0] + cL[9] * e[1] + cL[10] * e[2];
        zz[3] = mt.w + cL[12] * e[0] + cL[13] * e[1] + cL[14] * e[2] + cL[15] * e[3];
        z4[t] = make_float4(zz[0], zz[1], zz[2], zz[3]);
    }

    int t_init = own_hi - 1 + WARM;
    if (t_init > T_LEN - 2) t_init = T_LEN - 2;

    // carry init: filtered state at t_init+1 (exact if t_init+1 == T-1)
    float ms[4], Ps[16];
    {
        int ti = t_init + 1;
        float4 mv = fm4[ti];
        ms[0] = mv.x; ms[1] = mv.y; ms[2] = mv.z; ms[3] = mv.w;
#pragma unroll
        for (int q = 0; q < 4; ++q) {
            float4 v = fP4[ti * 4 + q];
            Ps[q * 4 + 0] = v.x; Ps[q * 4 + 1] = v.y; Ps[q * 4 + 2] = v.z; Ps[q * 4 + 3] = v.w;
        }
    }

    for (int t = t_init; t >= own_lo; --t) {
        float4 mfv = fm4[t];
        float mf_[4] = {mfv.x, mfv.y, mfv.z, mfv.w};
        float Pf[16];
#pragma unroll
        for (int q = 0; q < 4; ++q) {
            float4 v = fP4[t * 4 + q];
            Pf[q * 4 + 0] = v.x; Pf[q * 4 + 1] = v.y; Pf[q * 4 + 2] = v.z; Pf[q * 4 + 3] = v.w;
        }
        float4 pmv = pm4[t + 1];
        float mpn[4] = {pmv.x, pmv.y, pmv.z, pmv.w};
        float Ppn[16];
#pragma unroll
        for (int q = 0; q < 4; ++q) {
            float4 v = pP4[(t + 1) * 4 + q];
            Ppn[q * 4 + 0] = v.x; Ppn[q * 4 + 1] = v.y; Ppn[q * 4 + 2] = v.z; Ppn[q * 4 + 3] = v.w;
        }
        float cL[16], invd[4];
        chol4(Ppn, cL, invd);
        // B = A Pf ; X = Ppn^{-1} B ; G = X^T
        float B[16];
        mm4(a, Pf, B);
        float X[16];
        chosolve4(cL, invd, B, X);
        // m_s = mf + G (ms - mpn)
        float dm[4];
#pragma unroll
        for (int i = 0; i < 4; ++i) dm[i] = ms[i] - mpn[i];
        float msn[4];
#pragma unroll
        for (int i = 0; i < 4; ++i) {
            float s0 = mf_[i];
#pragma unroll
            for (int k = 0; k < 4; ++k) s0 += X[k * 4 + i] * dm[k];  // G[i][k] = X[k][i]
            msn[i] = s0;
        }
        // P_s = Pf + G (Ps - Ppn) G^T, symmetrized
        float DP[16];
#pragma unroll
        for (int i = 0; i < 16; ++i) DP[i] = Ps[i] - Ppn[i];
        float GD[16];
#pragma unroll
        for (int i = 0; i < 4; ++i)
#pragma unroll
            for (int j = 0; j < 4; ++j) {
                float s0 = 0.f;
#pragma unroll
                for (int k = 0; k < 4; ++k) s0 += X[k * 4 + i] * DP[k * 4 + j];
                GD[i * 4 + j] = s0;
            }
        float M[16];
#pragma unroll
        for (int i = 0; i < 4; ++i)
#pragma unroll
            for (int j = 0; j < 4; ++j) {
                float s0 = Pf[i * 4 + j];
#pragma unroll
                for (int k = 0; k < 4; ++k) s0 += GD[i * 4 + k] * X[k * 4 + j];  // G^T[k][j] = G[j][k] = X[k][j]
                M[i * 4 + j] = s0;
            }
        float Psn[16];
#pragma unroll
        for (int i = 0; i < 4; ++i)
#pragma unroll
            for (int j = 0; j < 4; ++j)
                Psn[i * 4 + j] = 0.5f * (M[i * 4 + j] + M[j * 4 + i]);
        if (t < own_hi) {
            sm4[t] = make_float4(msn[0], msn[1], msn[2], msn[3]);
#pragma unroll
            for (int q = 0; q < 4; ++q)
                sP4[t * 4 + q] = make_float4(Psn[q * 4 + 0], Psn[q * 4 + 1], Psn[q * 4 + 2], Psn[q * 4 + 3]);
            float Sz[16];
#pragma unroll
            for (int i = 0; i < 16; ++i) Sz[i] = Psn[i];
            Sz[0] += 1e-6f; Sz[5] += 1e-6f; Sz[10] += 1e-6f; Sz[15] += 1e-6f;
            float cz[16], izd[4];
            chol4(Sz, cz, izd);
            float4 ev = ep4[t];
            float e[4] = {ev.x, ev.y, ev.z, ev.w};
            float zz[4];
            zz[0] = msn[0] + cz[0] * e[0];
            zz[1] = msn[1] + cz[4] * e[0] + cz[5] * e[1];
            zz[2] = msn[2] + cz[8] * e[0] + cz[9] * e[1] + cz[10] * e[2];
            zz[3] = msn[3] + cz[12] * e[0] + cz[13] * e[1] + cz[14] * e[2] + cz[15] * e[3];
            z4[t] = make_float4(zz[0], zz[1], zz[2], zz[3]);
        }
#pragma unroll
        for (int i = 0; i < 4; ++i) ms[i] = msn[i];
#pragma unroll
        for (int i = 0; i < 16; ++i) Ps[i] = Psn[i];
    }
}

// ---------------- decoder: x_recon = relu(z Wd1 + bd1) Wd2 + bd2
__global__ __launch_bounds__(256) void decoder_kernel(
    const float* __restrict__ z, const float* __restrict__ Wd1, const float* __restrict__ bd1,
    const float* __restrict__ Wd2, const float* __restrict__ bd2,
    float* __restrict__ xr) {
    int lane = threadIdx.x & 63;
    int row = blockIdx.x * 4 + (threadIdx.x >> 6);
    float4 zv = reinterpret_cast<const float4*>(z)[row];
    float hd[H_DIM];
#pragma unroll
    for (int j = 0; j < H_DIM; ++j) {
        float s = bd1[j] + zv.x * Wd1[0 * H_DIM + j] + zv.y * Wd1[1 * H_DIM + j] +
                  zv.z * Wd1[2 * H_DIM + j] + zv.w * Wd1[3 * H_DIM + j];
        hd[j] = fmaxf(s, 0.f);
    }
    float4* out4 = reinterpret_cast<float4*>(xr + (size_t)row * D_DIM);
    const float4* bd2_4 = reinterpret_cast<const float4*>(bd2);
#pragma unroll
    for (int c = 0; c < 4; ++c) {
        int col4 = c * 64 + lane;
        int col = col4 * 4;
        float4 o = bd2_4[col4];
        float oe[4] = {o.x, o.y, o.z, o.w};
#pragma unroll
        for (int j = 0; j < H_DIM; ++j) {
            float w0 = Wd2[j * D_DIM + col + 0];
            float w1 = Wd2[j * D_DIM + col + 1];
            float w2 = Wd2[j * D_DIM + col + 2];
            float w3 = Wd2[j * D_DIM + col + 3];
            oe[0] += hd[j] * w0; oe[1] += hd[j] * w1; oe[2] += hd[j] * w2; oe[3] += hd[j] * w3;
        }
        out4[col4] = make_float4(oe[0], oe[1], oe[2], oe[3]);
    }
}

extern "C" void kernel_launch(void* const* d_in, const int* in_sizes, int n_in,
                              void* d_out, int out_size, void* d_ws, size_t ws_size,
                              hipStream_t stream) {
    const float* x    = (const float*)d_in[0];
    const float* eps  = (const float*)d_in[1];
    const float* W1   = (const float*)d_in[2];
    const float* b1   = (const float*)d_in[3];
    const float* Wmu  = (const float*)d_in[4];
    const float* bmu  = (const float*)d_in[5];
    const float* Wlv  = (const float*)d_in[6];
    const float* blv  = (const float*)d_in[7];
    const float* Wd1  = (const float*)d_in[8];
    const float* bd1  = (const float*)d_in[9];
    const float* Wd2  = (const float*)d_in[10];
    const float* bd2  = (const float*)d_in[11];
    const float* A    = (const float*)d_in[12];
    const float* bdyn = (const float*)d_in[13];
    const float* qp   = (const float*)d_in[14];

    float* out = (float*)d_out;
    size_t off = 0;
    float* xr_o  = out + off; off += (size_t)T_LEN * D_DIM;   // x_recon
    float* z_o   = out + off; off += (size_t)T_LEN * LD;      // z
    float* mu_o  = out + off; off += (size_t)T_LEN * LD;      // mu
    float* sig_o = out + off; off += (size_t)T_LEN * LD;      // sigma
    float* fm_o  = out + off; off += (size_t)T_LEN * LD;      // fm
    float* fP_o  = out + off; off += (size_t)T_LEN * LD * LD; // fP
    float* sm_o  = out + off; off += (size_t)T_LEN * LD;      // sm
    float* sP_o  = out + off; off += (size_t)T_LEN * LD * LD; // sP
    float* pm_o  = out + off; off += (size_t)T_LEN * LD;      // pm
    float* pP_o  = out + off; off += (size_t)T_LEN * LD * LD; // pP
    float* ll_o  = out + off;                                  // marginal_loglik

    hipMemsetAsync(ll_o, 0, sizeof(float), stream);

    encoder_kernel<<<T_LEN / 4, 256, 0, stream>>>(x, W1, b1, Wmu, bmu, Wlv, blv, mu_o, sig_o);
    filter_kernel<<<NCHUNK / 64, 64, 0, stream>>>(mu_o, sig_o, A, bdyn, qp, fm_o, fP_o, pm_o, pP_o, ll_o);
    smoother_kernel<<<NCHUNK / 64, 64, 0, stream>>>(fm_o, fP_o, pm_o, pP_o, A, eps, sm_o, sP_o, z_o);
    decoder_kernel<<<T_LEN / 4, 256, 0, stream>>>(z_o, Wd1, bd1, Wd2, bd2, xr_o);
}

// Round 2
// 378.437 us; speedup vs baseline: 1.3688x; 1.3688x over previous
//
#include <hip/hip_runtime.h>
#include <math.h>

#define T_LEN 32768
#define D_DIM 1024
#define LD 4
#define H_DIM 6
#define WARM 24

// log(2*pi)
#define LOG2PI 1.8378770664093453f

__device__ __forceinline__ float frcp(float x) {
    float r = __builtin_amdgcn_rcpf(x);
    return r * (2.0f - x * r);   // one Newton step -> ~0.5 ulp
}

// Cholesky of 4x4 SPD S (row-major). Fills lower cL, invd[j] = 1/cL[j][j].
__device__ __forceinline__ void chol4(const float* S, float* cL, float* invd) {
#pragma unroll
    for (int j = 0; j < 4; ++j) {
        float d = S[j * 4 + j];
#pragma unroll
        for (int k = 0; k < j; ++k) d -= cL[j * 4 + k] * cL[j * 4 + k];
        float c = sqrtf(d);
        cL[j * 4 + j] = c;
        float id = frcp(c);
        invd[j] = id;
#pragma unroll
        for (int i = j + 1; i < 4; ++i) {
            float v = S[i * 4 + j];
#pragma unroll
            for (int k = 0; k < j; ++k) v -= cL[i * 4 + k] * cL[j * 4 + k];
            cL[i * 4 + j] = v * id;
        }
    }
}

// X = S^{-1} B  (4 RHS = columns of B), S = cL cL^T
__device__ __forceinline__ void chosolve4(const float* cL, const float* invd,
                                          const float* B, float* X) {
#pragma unroll
    for (int c = 0; c < 4; ++c) {
        float y0 = B[0 * 4 + c] * invd[0];
        float y1 = (B[1 * 4 + c] - cL[4] * y0) * invd[1];
        float y2 = (B[2 * 4 + c] - cL[8] * y0 - cL[9] * y1) * invd[2];
        float y3 = (B[3 * 4 + c] - cL[12] * y0 - cL[13] * y1 - cL[14] * y2) * invd[3];
        float x3 = y3 * invd[3];
        float x2 = (y2 - cL[14] * x3) * invd[2];
        float x1 = (y1 - cL[9] * x2 - cL[13] * x3) * invd[1];
        float x0 = (y0 - cL[4] * x1 - cL[8] * x2 - cL[12] * x3) * invd[0];
        X[0 * 4 + c] = x0; X[1 * 4 + c] = x1; X[2 * 4 + c] = x2; X[3 * 4 + c] = x3;
    }
}

__device__ __forceinline__ void mm4(const float* A, const float* B, float* C) {
#pragma unroll
    for (int i = 0; i < 4; ++i)
#pragma unroll
        for (int j = 0; j < 4; ++j) {
            float s = 0.f;
#pragma unroll
            for (int k = 0; k < 4; ++k) s += A[i * 4 + k] * B[k * 4 + j];
            C[i * 4 + j] = s;
        }
}

// ---------------- encoder: h = relu(xW1+b1); mu = hWmu+bmu; sigma = exp(0.5(hWlv+blv))
__global__ __launch_bounds__(256) void encoder_kernel(
    const float* __restrict__ x, const float* __restrict__ W1, const float* __restrict__ b1,
    const float* __restrict__ Wmu, const float* __restrict__ bmu,
    const float* __restrict__ Wlv, const float* __restrict__ blv,
    float* __restrict__ mu_o, float* __restrict__ sig_o) {
    int lane = threadIdx.x & 63;
    int row = blockIdx.x * 4 + (threadIdx.x >> 6);
    const float4* x4 = reinterpret_cast<const float4*>(x + (size_t)row * D_DIM);
    const float4* w4 = reinterpret_cast<const float4*>(W1);
    float acc[H_DIM];
#pragma unroll
    for (int j = 0; j < H_DIM; ++j) acc[j] = 0.f;
#pragma unroll
    for (int c = 0; c < 4; ++c) {
        int idx4 = c * 64 + lane;      // float4 index within row
        float4 xv = x4[idx4];
        float w[24];
        int wb = idx4 * 6;             // float4 index into W1
#pragma unroll
        for (int q = 0; q < 6; ++q) {
            float4 wv = w4[wb + q];
            w[q * 4 + 0] = wv.x; w[q * 4 + 1] = wv.y; w[q * 4 + 2] = wv.z; w[q * 4 + 3] = wv.w;
        }
        float xe[4] = {xv.x, xv.y, xv.z, xv.w};
#pragma unroll
        for (int e = 0; e < 4; ++e)
#pragma unroll
            for (int j = 0; j < H_DIM; ++j)
                acc[j] += xe[e] * w[e * 6 + j];
    }
#pragma unroll
    for (int off = 32; off; off >>= 1)
#pragma unroll
        for (int j = 0; j < H_DIM; ++j)
            acc[j] += __shfl_xor(acc[j], off, 64);
    float h[H_DIM];
#pragma unroll
    for (int j = 0; j < H_DIM; ++j) h[j] = fmaxf(acc[j] + b1[j], 0.f);
    if (lane < LD) {
        int i = lane;
        float muv = bmu[i], lvv = blv[i];
#pragma unroll
        for (int j = 0; j < H_DIM; ++j) {
            muv += h[j] * Wmu[j * LD + i];
            lvv += h[j] * Wlv[j * LD + i];
        }
        mu_o[(size_t)row * LD + i] = muv;
        sig_o[(size_t)row * LD + i] = expf(0.5f * lvv);
    }
}

// ---------------- filter: per-timestep thread, warm-started WARM steps back
__global__ __launch_bounds__(256) void filter_kernel(
    const float* __restrict__ mu, const float* __restrict__ sigma,
    const float* __restrict__ Ain, const float* __restrict__ b_dyn,
    const float* __restrict__ qp,
    float* __restrict__ fm, float* __restrict__ fP,
    float* __restrict__ pm, float* __restrict__ pP, float* __restrict__ ll_out) {
    int t_own = blockIdx.x * blockDim.x + threadIdx.x;

    float a[16], b[4];
#pragma unroll
    for (int i = 0; i < 16; ++i) a[i] = Ain[i];
#pragma unroll
    for (int i = 0; i < 4; ++i) b[i] = b_dyn[i];

    // Q = L L^T, L lower-tri from qp (row-major tril order), diag = exp(raw)
    float Lm[16];
#pragma unroll
    for (int i = 0; i < 16; ++i) Lm[i] = 0.f;
    Lm[0] = expf(qp[0]);
    Lm[4] = qp[1];  Lm[5] = expf(qp[2]);
    Lm[8] = qp[3];  Lm[9] = qp[4];  Lm[10] = expf(qp[5]);
    Lm[12] = qp[6]; Lm[13] = qp[7]; Lm[14] = qp[8]; Lm[15] = expf(qp[9]);
    float Q[16];
#pragma unroll
    for (int i = 0; i < 4; ++i)
#pragma unroll
        for (int j = 0; j < 4; ++j) {
            float s = 0.f;
#pragma unroll
            for (int k = 0; k < 4; ++k) s += Lm[i * 4 + k] * Lm[j * 4 + k];
            Q[i * 4 + j] = s;
        }

    int start = t_own - WARM;
    if (start < 0) start = 0;

    float m[4] = {0.f, 0.f, 0.f, 0.f};
    float P[16];
#pragma unroll
    for (int i = 0; i < 16; ++i) P[i] = 0.f;
    P[0] = P[5] = P[10] = P[15] = 1.f;

    const float4* mu4 = reinterpret_cast<const float4*>(mu);
    const float4* sg4 = reinterpret_cast<const float4*>(sigma);

    float mp[4], Pp[16], mf[4], Pf[16], cL[16], invd[4], innov[4];

    for (int t = start; t <= t_own; ++t) {
        float4 yv = mu4[t];
        float4 rv = sg4[t];
        float y[4] = {yv.x, yv.y, yv.z, yv.w};
        // m_pred = A m + b
#pragma unroll
        for (int i = 0; i < 4; ++i) {
            float s0 = b[i];
#pragma unroll
            for (int k = 0; k < 4; ++k) s0 += a[i * 4 + k] * m[k];
            mp[i] = s0;
        }
        // P_pred = A P A^T + Q
        float AP[16];
        mm4(a, P, AP);
#pragma unroll
        for (int i = 0; i < 4; ++i)
#pragma unroll
            for (int j = 0; j < 4; ++j) {
                float s0 = Q[i * 4 + j];
#pragma unroll
                for (int k = 0; k < 4; ++k) s0 += AP[i * 4 + k] * a[j * 4 + k];
                Pp[i * 4 + j] = s0;
            }
        // S = Pp + diag(r)
        float S[16];
#pragma unroll
        for (int i = 0; i < 16; ++i) S[i] = Pp[i];
        S[0] += rv.x; S[5] += rv.y; S[10] += rv.z; S[15] += rv.w;
        chol4(S, cL, invd);
        // X = S^{-1} Pp ; K = X^T
        float X[16];
        chosolve4(cL, invd, Pp, X);
#pragma unroll
        for (int i = 0; i < 4; ++i) innov[i] = y[i] - mp[i];
#pragma unroll
        for (int i = 0; i < 4; ++i) {
            float s0 = mp[i];
#pragma unroll
            for (int k = 0; k < 4; ++k) s0 += X[k * 4 + i] * innov[k];  // K[i][k] = X[k][i]
            mf[i] = s0;
        }
        // Pf = (I - K) Pp, symmetrized
        float M[16];
#pragma unroll
        for (int i = 0; i < 4; ++i)
#pragma unroll
            for (int j = 0; j < 4; ++j) {
                float s0 = Pp[i * 4 + j];
#pragma unroll
                for (int k = 0; k < 4; ++k) s0 -= X[k * 4 + i] * Pp[k * 4 + j];
                M[i * 4 + j] = s0;
            }
#pragma unroll
        for (int i = 0; i < 4; ++i)
#pragma unroll
            for (int j = 0; j < 4; ++j)
                Pf[i * 4 + j] = 0.5f * (M[i * 4 + j] + M[j * 4 + i]);
#pragma unroll
        for (int i = 0; i < 4; ++i) m[i] = mf[i];
#pragma unroll
        for (int i = 0; i < 16; ++i) P[i] = Pf[i];
    }

    // stores + ll for own step
    float w0 = innov[0] * invd[0];
    float w1 = (innov[1] - cL[4] * w0) * invd[1];
    float w2 = (innov[2] - cL[8] * w0 - cL[9] * w1) * invd[2];
    float w3 = (innov[3] - cL[12] * w0 - cL[13] * w1 - cL[14] * w2) * invd[3];
    float wsq = w0 * w0 + w1 * w1 + w2 * w2 + w3 * w3;
    float proddiag = cL[0] * cL[5] * cL[10] * cL[15];
    float ll_term = -0.5f * (4.f * LOG2PI + wsq) - logf(proddiag);

    float4* fm4 = reinterpret_cast<float4*>(fm);
    float4* pm4 = reinterpret_cast<float4*>(pm);
    float4* fP4 = reinterpret_cast<float4*>(fP);
    float4* pP4 = reinterpret_cast<float4*>(pP);
    fm4[t_own] = make_float4(mf[0], mf[1], mf[2], mf[3]);
    pm4[t_own] = make_float4(mp[0], mp[1], mp[2], mp[3]);
#pragma unroll
    for (int q = 0; q < 4; ++q) {
        fP4[t_own * 4 + q] = make_float4(Pf[q * 4 + 0], Pf[q * 4 + 1], Pf[q * 4 + 2], Pf[q * 4 + 3]);
        pP4[t_own * 4 + q] = make_float4(Pp[q * 4 + 0], Pp[q * 4 + 1], Pp[q * 4 + 2], Pp[q * 4 + 3]);
    }

    // wave-level reduce then one atomic per wave
#pragma unroll
    for (int off = 32; off; off >>= 1)
        ll_term += __shfl_xor(ll_term, off, 64);
    if ((threadIdx.x & 63) == 0) atomicAdd(ll_out, ll_term);
}

// ---------------- smoother (+ sampling z): per-timestep thread
__global__ __launch_bounds__(256) void smoother_kernel(
    const float* __restrict__ fm, const float* __restrict__ fP,
    const float* __restrict__ pm, const float* __restrict__ pP,
    const float* __restrict__ Ain, const float* __restrict__ eps,
    float* __restrict__ sm, float* __restrict__ sP, float* __restrict__ z) {
    int c = blockIdx.x * blockDim.x + threadIdx.x;

    const float4* fm4 = reinterpret_cast<const float4*>(fm);
    const float4* fP4 = reinterpret_cast<const float4*>(fP);
    const float4* pm4 = reinterpret_cast<const float4*>(pm);
    const float4* pP4 = reinterpret_cast<const float4*>(pP);
    const float4* ep4 = reinterpret_cast<const float4*>(eps);
    float4* sm4 = reinterpret_cast<float4*>(sm);
    float4* sP4 = reinterpret_cast<float4*>(sP);
    float4* z4 = reinterpret_cast<float4*>(z);

    if (c == T_LEN - 1) {
        // terminal: smoothed == filtered
        int t = T_LEN - 1;
        float4 mt = fm4[t];
        float Pt[16];
#pragma unroll
        for (int q = 0; q < 4; ++q) {
            float4 v = fP4[t * 4 + q];
            Pt[q * 4 + 0] = v.x; Pt[q * 4 + 1] = v.y; Pt[q * 4 + 2] = v.z; Pt[q * 4 + 3] = v.w;
        }
        sm4[t] = mt;
#pragma unroll
        for (int q = 0; q < 4; ++q)
            sP4[t * 4 + q] = make_float4(Pt[q * 4 + 0], Pt[q * 4 + 1], Pt[q * 4 + 2], Pt[q * 4 + 3]);
        float Sz[16];
#pragma unroll
        for (int i = 0; i < 16; ++i) Sz[i] = Pt[i];
        Sz[0] += 1e-6f; Sz[5] += 1e-6f; Sz[10] += 1e-6f; Sz[15] += 1e-6f;
        float cLt[16], invdt[4];
        chol4(Sz, cLt, invdt);
        float4 ev = ep4[t];
        float e[4] = {ev.x, ev.y, ev.z, ev.w};
        float zz[4];
        zz[0] = mt.x + cLt[0] * e[0];
        zz[1] = mt.y + cLt[4] * e[0] + cLt[5] * e[1];
        zz[2] = mt.z + cLt[8] * e[0] + cLt[9] * e[1] + cLt[10] * e[2];
        zz[3] = mt.w + cLt[12] * e[0] + cLt[13] * e[1] + cLt[14] * e[2] + cLt[15] * e[3];
        z4[t] = make_float4(zz[0], zz[1], zz[2], zz[3]);
        return;
    }

    float a[16];
#pragma unroll
    for (int i = 0; i < 16; ++i) a[i] = Ain[i];

    int t_init = c + WARM;
    if (t_init > T_LEN - 2) t_init = T_LEN - 2;

    // carry init: filtered state at t_init+1 (exact if t_init+1 == T-1)
    float ms[4], Ps[16];
    {
        int ti = t_init + 1;
        float4 mv = fm4[ti];
        ms[0] = mv.x; ms[1] = mv.y; ms[2] = mv.z; ms[3] = mv.w;
#pragma unroll
        for (int q = 0; q < 4; ++q) {
            float4 v = fP4[ti * 4 + q];
            Ps[q * 4 + 0] = v.x; Ps[q * 4 + 1] = v.y; Ps[q * 4 + 2] = v.z; Ps[q * 4 + 3] = v.w;
        }
    }

    for (int t = t_init; t >= c; --t) {
        float4 mfv = fm4[t];
        float mf_[4] = {mfv.x, mfv.y, mfv.z, mfv.w};
        float Pf[16];
#pragma unroll
        for (int q = 0; q < 4; ++q) {
            float4 v = fP4[t * 4 + q];
            Pf[q * 4 + 0] = v.x; Pf[q * 4 + 1] = v.y; Pf[q * 4 + 2] = v.z; Pf[q * 4 + 3] = v.w;
        }
        float4 pmv = pm4[t + 1];
        float mpn[4] = {pmv.x, pmv.y, pmv.z, pmv.w};
        float Ppn[16];
#pragma unroll
        for (int q = 0; q < 4; ++q) {
            float4 v = pP4[(t + 1) * 4 + q];
            Ppn[q * 4 + 0] = v.x; Ppn[q * 4 + 1] = v.y; Ppn[q * 4 + 2] = v.z; Ppn[q * 4 + 3] = v.w;
        }
        float cL[16], invd[4];
        chol4(Ppn, cL, invd);
        // B = A Pf ; X = Ppn^{-1} B ; G = X^T
        float B[16];
        mm4(a, Pf, B);
        float X[16];
        chosolve4(cL, invd, B, X);
        // m_s = mf + G (ms - mpn)
        float dm[4];
#pragma unroll
        for (int i = 0; i < 4; ++i) dm[i] = ms[i] - mpn[i];
        float msn[4];
#pragma unroll
        for (int i = 0; i < 4; ++i) {
            float s0 = mf_[i];
#pragma unroll
            for (int k = 0; k < 4; ++k) s0 += X[k * 4 + i] * dm[k];  // G[i][k] = X[k][i]
            msn[i] = s0;
        }
        // P_s = Pf + G (Ps - Ppn) G^T, symmetrized
        float DP[16];
#pragma unroll
        for (int i = 0; i < 16; ++i) DP[i] = Ps[i] - Ppn[i];
        float GD[16];
#pragma unroll
        for (int i = 0; i < 4; ++i)
#pragma unroll
            for (int j = 0; j < 4; ++j) {
                float s0 = 0.f;
#pragma unroll
                for (int k = 0; k < 4; ++k) s0 += X[k * 4 + i] * DP[k * 4 + j];
                GD[i * 4 + j] = s0;
            }
        float M[16];
#pragma unroll
        for (int i = 0; i < 4; ++i)
#pragma unroll
            for (int j = 0; j < 4; ++j) {
                float s0 = Pf[i * 4 + j];
#pragma unroll
                for (int k = 0; k < 4; ++k) s0 += GD[i * 4 + k] * X[k * 4 + j];  // G^T[k][j] = X[k][j]
                M[i * 4 + j] = s0;
            }
#pragma unroll
        for (int i = 0; i < 4; ++i)
#pragma unroll
            for (int j = 0; j < 4; ++j) {
                float v = 0.5f * (M[i * 4 + j] + M[j * 4 + i]);
                Ps[i * 4 + j] = v;
            }
#pragma unroll
        for (int i = 0; i < 4; ++i) ms[i] = msn[i];
    }

    // own-step outputs: (ms, Ps) now hold smoothed state at t = c
    sm4[c] = make_float4(ms[0], ms[1], ms[2], ms[3]);
#pragma unroll
    for (int q = 0; q < 4; ++q)
        sP4[c * 4 + q] = make_float4(Ps[q * 4 + 0], Ps[q * 4 + 1], Ps[q * 4 + 2], Ps[q * 4 + 3]);
    float Sz[16];
#pragma unroll
    for (int i = 0; i < 16; ++i) Sz[i] = Ps[i];
    Sz[0] += 1e-6f; Sz[5] += 1e-6f; Sz[10] += 1e-6f; Sz[15] += 1e-6f;
    float cz[16], izd[4];
    chol4(Sz, cz, izd);
    float4 ev = ep4[c];
    float e[4] = {ev.x, ev.y, ev.z, ev.w};
    float zz[4];
    zz[0] = ms[0] + cz[0] * e[0];
    zz[1] = ms[1] + cz[4] * e[0] + cz[5] * e[1];
    zz[2] = ms[2] + cz[8] * e[0] + cz[9] * e[1] + cz[10] * e[2];
    zz[3] = ms[3] + cz[12] * e[0] + cz[13] * e[1] + cz[14] * e[2] + cz[15] * e[3];
    z4[c] = make_float4(zz[0], zz[1], zz[2], zz[3]);
}

// ---------------- decoder: x_recon = relu(z Wd1 + bd1) Wd2 + bd2
__global__ __launch_bounds__(256) void decoder_kernel(
    const float* __restrict__ z, const float* __restrict__ Wd1, const float* __restrict__ bd1,
    const float* __restrict__ Wd2, const float* __restrict__ bd2,
    float* __restrict__ xr) {
    int lane = threadIdx.x & 63;
    int row = blockIdx.x * 4 + (threadIdx.x >> 6);
    float4 zv = reinterpret_cast<const float4*>(z)[row];
    float hd[H_DIM];
#pragma unroll
    for (int j = 0; j < H_DIM; ++j) {
        float s = bd1[j] + zv.x * Wd1[0 * H_DIM + j] + zv.y * Wd1[1 * H_DIM + j] +
                  zv.z * Wd1[2 * H_DIM + j] + zv.w * Wd1[3 * H_DIM + j];
        hd[j] = fmaxf(s, 0.f);
    }
    float4* out4 = reinterpret_cast<float4*>(xr + (size_t)row * D_DIM);
    const float4* bd2_4 = reinterpret_cast<const float4*>(bd2);
#pragma unroll
    for (int c = 0; c < 4; ++c) {
        int col4 = c * 64 + lane;
        int col = col4 * 4;
        float4 o = bd2_4[col4];
        float oe[4] = {o.x, o.y, o.z, o.w};
#pragma unroll
        for (int j = 0; j < H_DIM; ++j) {
            float w0 = Wd2[j * D_DIM + col + 0];
            float w1 = Wd2[j * D_DIM + col + 1];
            float w2 = Wd2[j * D_DIM + col + 2];
            float w3 = Wd2[j * D_DIM + col + 3];
            oe[0] += hd[j] * w0; oe[1] += hd[j] * w1; oe[2] += hd[j] * w2; oe[3] += hd[j] * w3;
        }
        out4[col4] = make_float4(oe[0], oe[1], oe[2], oe[3]);
    }
}

extern "C" void kernel_launch(void* const* d_in, const int* in_sizes, int n_in,
                              void* d_out, int out_size, void* d_ws, size_t ws_size,
                              hipStream_t stream) {
    const float* x    = (const float*)d_in[0];
    const float* eps  = (const float*)d_in[1];
    const float* W1   = (const float*)d_in[2];
    const float* b1   = (const float*)d_in[3];
    const float* Wmu  = (const float*)d_in[4];
    const float* bmu  = (const float*)d_in[5];
    const float* Wlv  = (const float*)d_in[6];
    const float* blv  = (const float*)d_in[7];
    const float* Wd1  = (const float*)d_in[8];
    const float* bd1  = (const float*)d_in[9];
    const float* Wd2  = (const float*)d_in[10];
    const float* bd2  = (const float*)d_in[11];
    const float* A    = (const float*)d_in[12];
    const float* bdyn = (const float*)d_in[13];
    const float* qp   = (const float*)d_in[14];

    float* out = (float*)d_out;
    size_t off = 0;
    float* xr_o  = out + off; off += (size_t)T_LEN * D_DIM;   // x_recon
    float* z_o   = out + off; off += (size_t)T_LEN * LD;      // z
    float* mu_o  = out + off; off += (size_t)T_LEN * LD;      // mu
    float* sig_o = out + off; off += (size_t)T_LEN * LD;      // sigma
    float* fm_o  = out + off; off += (size_t)T_LEN * LD;      // fm
    float* fP_o  = out + off; off += (size_t)T_LEN * LD * LD; // fP
    float* sm_o  = out + off; off += (size_t)T_LEN * LD;      // sm
    float* sP_o  = out + off; off += (size_t)T_LEN * LD * LD; // sP
    float* pm_o  = out + off; off += (size_t)T_LEN * LD;      // pm
    float* pP_o  = out + off; off += (size_t)T_LEN * LD * LD; // pP
    float* ll_o  = out + off;                                  // marginal_loglik

    hipMemsetAsync(ll_o, 0, sizeof(float), stream);

    encoder_kernel<<<T_LEN / 4, 256, 0, stream>>>(x, W1, b1, Wmu, bmu, Wlv, blv, mu_o, sig_o);
    filter_kernel<<<T_LEN / 256, 256, 0, stream>>>(mu_o, sig_o, A, bdyn, qp, fm_o, fP_o, pm_o, pP_o, ll_o);
    smoother_kernel<<<T_LEN / 256, 256, 0, stream>>>(fm_o, fP_o, pm_o, pP_o, A, eps, sm_o, sP_o, z_o);
    decoder_kernel<<<T_LEN / 4, 256, 0, stream>>>(z_o, Wd1, bd1, Wd2, bd2, xr_o);
}